// Round 20
// baseline (204.722 us; speedup 1.0000x reference)
//
#include <hip/hip_runtime.h>
#include <hip/hip_bf16.h>

typedef __attribute__((ext_vector_type(8))) short short8;
typedef __attribute__((ext_vector_type(4))) float f32x4;

#define MFMA16(a, b, c) __builtin_amdgcn_mfma_f32_16x16x32_bf16((a), (b), (c), 0, 0, 0)

__device__ __forceinline__ unsigned short f2bf(float x) {
    union { float f; unsigned int u; } v; v.f = x;
    unsigned int u = v.u;
    return (unsigned short)((u + 0x7FFFu + ((u >> 16) & 1u)) >> 16);
}

__device__ __forceinline__ float pow14(float x) {
    return exp2f(1.4f * log2f(x));
}

__device__ __forceinline__ short8 ld8(const unsigned short* p) {
    return *reinterpret_cast<const short8*>(p);
}

__device__ __forceinline__ void gld16(const void* src, const unsigned char* dst) {
    __builtin_amdgcn_global_load_lds(
        (const __attribute__((address_space(1))) void*)src,
        (__attribute__((address_space(3))) void*)dst, 16, 0, 0);
}

// ---- K0: bbn fp32 -> bf16 (plain + row-swizzled copy), row sums s[i] ---------
__global__ void k_prep_bbn(const float* __restrict__ bbn, unsigned short* __restrict__ bbn_h,
                           unsigned short* __restrict__ bbn_swz, float* __restrict__ s) {
    int row = blockIdx.x * 4 + (threadIdx.x >> 6);
    int lane = threadIdx.x & 63;
    float x = bbn[row * 64 + lane];
    unsigned short h = f2bf(x);
    bbn_h[row * 64 + lane] = h;
    bbn_swz[row * 64 + (lane ^ ((row & 7) << 3))] = h;
    float v = x;
    #pragma unroll
    for (int m = 1; m < 64; m <<= 1) v += __shfl_xor(v, m);
    if (lane == 0) s[row] = v;
}

__global__ void k_zero_d(float* __restrict__ dd) {
    dd[blockIdx.x * 1024 + threadIdx.x] = 0.f;
}

// ---- K0b/K2: transpose (+optional rsqrt(d) row scale, optional swizzle) ------
__global__ void k_transpose_scale(const float* __restrict__ in, unsigned short* __restrict__ out,
                                  const float* __restrict__ dvec, int K, int N, int swz) {
    __shared__ float tile[64][65];
    int tiles_k = K >> 6;
    int tk = blockIdx.x % tiles_k, tn = blockIdx.x / tiles_k;
    int k0 = tk * 64, n0 = tn * 64;
    int c = threadIdx.x & 63, rq = threadIdx.x >> 6;
    #pragma unroll
    for (int i = 0; i < 16; ++i) {
        int r = rq + 4 * i;
        float sc = dvec ? rsqrtf(dvec[k0 + r]) : 1.0f;
        tile[r][c] = in[(size_t)(k0 + r) * N + n0 + c] * sc;
    }
    __syncthreads();
    #pragma unroll
    for (int i = 0; i < 16; ++i) {
        int r = rq + 4 * i;
        int cc = swz ? (c ^ ((r & 7) << 3)) : c;
        out[(size_t)(n0 + r) * K + k0 + cc] = f2bf(tile[c][r]);
    }
}

// ---- K1: materialize A (swizzled bf16) + degree d[i] --------------------------
// 512 blocks = 128 i-tiles x 4 j-quarters; 512 threads, 8 waves, 2 blocks/CU.
// Triple-buffered Aj staged for t+2; s-quarter in LDS; counted barrier vmcnt(2).
__global__ __launch_bounds__(512, 4) void k_gen_adj(const unsigned short* __restrict__ bbn_h,
                                                    const unsigned short* __restrict__ bbn_swz,
                                                    const float* __restrict__ s,
                                                    unsigned short* __restrict__ A_swz,
                                                    float* __restrict__ dd) {
    int bx = blockIdx.x;
    int it = bx >> 2, jq = bx & 3;
    int i0 = it * 64, jbase = jq * 2048;

    int tid = threadIdx.x;
    int w = tid >> 6, l = tid & 63, g = l >> 4, c = l & 15;
    int gi = w & 3, gj2 = w >> 2;

    const unsigned short* ap = bbn_h + (i0 + gi * 16 + c) * 64;
    short8 ga0 = ld8(ap), ga1 = ld8(ap + 32);
    float si = s[i0 + gi * 16 + c];

    __shared__ unsigned char AjldsF[3 * 8192];
    __shared__ unsigned char OutldsF[2 * 8192];
    __shared__ float sLDS[2048];

    const unsigned short* ajbase = bbn_swz + (jbase + w * 8 + (l >> 3)) * 64 + (l & 7) * 8;
    const int ajdst = w * 1024;

    const int sw = (c & 7) << 4;
    const int gj0 = gj2 * 2, gj1 = gj2 * 2 + 1;
    const int bo00 = (gj0 * 16 + c) * 128 + ((g * 16) ^ sw);
    const int bo01 = (gj0 * 16 + c) * 128 + ((64 + g * 16) ^ sw);
    const int bo10 = (gj1 * 16 + c) * 128 + ((g * 16) ^ sw);
    const int bo11 = (gj1 * 16 + c) * 128 + ((64 + g * 16) ^ sw);
    const int wr0 = ((gi * 16 + c) * 128 + (gj0 * 16 + g * 4) * 2) ^ sw;
    const int wr1 = ((gi * 16 + c) * 128 + (gj1 * 16 + g * 4) * 2) ^ sw;

    float racc = 0.f;

#define GEN_TILE(T) do {                                                           \
    const unsigned char* aj = &AjldsF[((T) % 3) * 8192];                           \
    unsigned char* outp = &OutldsF[((T) & 1) * 8192];                              \
    _Pragma("unroll")                                                              \
    for (int p = 0; p < 2; ++p) {                                                  \
        short8 gb0 = *reinterpret_cast<const short8*>(&aj[p ? bo10 : bo00]);       \
        short8 gb1 = *reinterpret_cast<const short8*>(&aj[p ? bo11 : bo01]);       \
        f32x4 sj4 = *reinterpret_cast<const f32x4*>(                               \
            &sLDS[(T) * 64 + (p ? gj1 : gj0) * 16 + g * 4]);                       \
        f32x4 gf = {0.f, 0.f, 0.f, 0.f};                                           \
        gf = MFMA16(gb0, ga0, gf);                                                 \
        gf = MFMA16(gb1, ga1, gf);                                                 \
        float t0 = fmaf(2.f, gf[0], -(si + sj4[0]));                               \
        float t1 = fmaf(2.f, gf[1], -(si + sj4[1]));                               \
        float t2 = fmaf(2.f, gf[2], -(si + sj4[2]));                               \
        float t3 = fmaf(2.f, gf[3], -(si + sj4[3]));                               \
        float u0 = pow14(fmaxf(fmaf(fabsf(t0), -0.015625f, 1.f), 0.f));            \
        float u1 = pow14(fmaxf(fmaf(fabsf(t1), -0.015625f, 1.f), 0.f));            \
        float u2 = pow14(fmaxf(fmaf(fabsf(t2), -0.015625f, 1.f), 0.f));            \
        float u3 = pow14(fmaxf(fmaf(fabsf(t3), -0.015625f, 1.f), 0.f));            \
        racc += (u0 + u1) + (u2 + u3);                                             \
        unsigned short p0 = f2bf(u0), p1 = f2bf(u1), p2 = f2bf(u2), p3 = f2bf(u3); \
        *reinterpret_cast<uint2*>(&outp[p ? wr1 : wr0]) =                          \
            make_uint2((unsigned)p0 | ((unsigned)p1 << 16),                        \
                       (unsigned)p2 | ((unsigned)p3 << 16));                       \
    }                                                                              \
} while (0)

    gld16(s + jbase + w * 256 + l * 4, (unsigned char*)sLDS + w * 1024);
    gld16(ajbase, &AjldsF[ajdst]);
    gld16(ajbase + 4096, &AjldsF[8192 + ajdst]);
    asm volatile("s_waitcnt vmcnt(1) lgkmcnt(0)\ns_barrier" ::: "memory");

    for (int t = 0; t < 32; ++t) {
        if (t > 0) {
            int row = tid >> 3, seg = tid & 7;
            uint4 v = *reinterpret_cast<const uint4*>(&OutldsF[((t - 1) & 1) * 8192 + tid * 16]);
            *reinterpret_cast<uint4*>(A_swz + (size_t)(i0 + row) * 8192 + jbase + (t - 1) * 64 + seg * 8) = v;
        }
        int jt = (t + 2 < 32) ? t + 2 : 31;
        gld16(ajbase + jt * 4096, &AjldsF[((t + 2) % 3) * 8192 + ajdst]);
        GEN_TILE(t);
        if (t == 0) { asm volatile("s_waitcnt vmcnt(1) lgkmcnt(0)\ns_barrier" ::: "memory"); }
        else        { asm volatile("s_waitcnt vmcnt(2) lgkmcnt(0)\ns_barrier" ::: "memory"); }
    }
    {
        int row = tid >> 3, seg = tid & 7;
        uint4 v = *reinterpret_cast<const uint4*>(&OutldsF[(31 & 1) * 8192 + tid * 16]);
        *reinterpret_cast<uint4*>(A_swz + (size_t)(i0 + row) * 8192 + jbase + 31 * 64 + seg * 8) = v;
    }
#undef GEN_TILE

    racc += __shfl_xor(racc, 16);
    racc += __shfl_xor(racc, 32);
    if (g == 0) atomicAdd(&dd[i0 + gi * 16 + c], racc);
}

// ---- K3: split-K GEMM, BM=64 x BN=512 (full width), Ksplit=4 ------------------
// 512 blocks = 128 row x 4 ks = 2 blocks/CU; 512 thr, 8 waves, 64x64/wave
// (16 MAC/LDS-byte). A read exactly once. Single-buffered 72KB LDS, m97
// 2-barrier loop — co-resident block hides the vmcnt(0) drain.
__global__ __launch_bounds__(512, 4) void k_spectral(const unsigned short* __restrict__ A_swz,
                                                     const unsigned short* __restrict__ cbn_sT,
                                                     float* __restrict__ hpart) {
    int bx = blockIdx.x;
    int row = bx >> 2, ks = bx & 3;
    int i0 = row * 64, k0 = ks * 2048;

    int tid = threadIdx.x;
    int w = tid >> 6, l = tid & 63, g = l >> 4, c = l & 15;
    int lrow = l >> 3, lseg = l & 7;

    __shared__ unsigned char Alds[8192];
    __shared__ unsigned char Blds[65536];

    f32x4 acc[4][4] = {};

    const unsigned short* srcA = A_swz + (size_t)(i0 + w * 8 + lrow) * 8192 + k0 + lseg * 8;
    const unsigned short* srcB = cbn_sT + (size_t)(w * 8 + lrow) * 8192 + k0 + lseg * 8;
    const int sw = (c & 7) << 4;

    for (int t = 0; t < 32; ++t) {
        int jt = t * 64;
        gld16(srcA + jt, &Alds[w * 1024]);
        #pragma unroll
        for (int q = 0; q < 8; ++q)
            gld16(srcB + (size_t)(q * 64) * 8192 + jt, &Blds[(q * 64 + w * 8) * 128]);
        asm volatile("s_waitcnt vmcnt(0) lgkmcnt(0)\ns_barrier" ::: "memory");

        #pragma unroll
        for (int kk = 0; kk < 2; ++kk) {
            short8 af[4], bf[4];
            #pragma unroll
            for (int mi = 0; mi < 4; ++mi)
                af[mi] = *reinterpret_cast<const short8*>(
                    &Alds[(mi * 16 + c) * 128 + ((kk * 64 + g * 16) ^ sw)]);
            #pragma unroll
            for (int nn = 0; nn < 4; ++nn)
                bf[nn] = *reinterpret_cast<const short8*>(
                    &Blds[(w * 64 + nn * 16 + c) * 128 + ((kk * 64 + g * 16) ^ sw)]);
            __builtin_amdgcn_s_setprio(1);
            #pragma unroll
            for (int mi = 0; mi < 4; ++mi)
                #pragma unroll
                for (int nn = 0; nn < 4; ++nn)
                    acc[mi][nn] = MFMA16(af[mi], bf[nn], acc[mi][nn]);
            __builtin_amdgcn_s_setprio(0);
        }
        asm volatile("s_waitcnt lgkmcnt(0)\ns_barrier" ::: "memory");
    }

    float* hp = hpart + (size_t)bx * 32768;
    #pragma unroll
    for (int mi = 0; mi < 4; ++mi)
        #pragma unroll
        for (int r = 0; r < 4; ++r) {
            int lr = mi * 16 + g * 4 + r;
            #pragma unroll
            for (int nn = 0; nn < 4; ++nn)
                hp[lr * 512 + w * 64 + nn * 16 + c] = acc[mi][nn][r];
        }
}

// ---- K3b: h = bf16( (Σ_ks hpart) * dinv_i ); 4096 blocks x 256 thr x 4 elems --
__global__ __launch_bounds__(256) void k_reduce(const float* __restrict__ hpart,
                                                const float* __restrict__ dd,
                                                unsigned short* __restrict__ h) {
    size_t flat = ((size_t)blockIdx.x * 256 + threadIdx.x) * 4;
    int i = (int)(flat >> 9), n = (int)(flat & 511);
    int row = i >> 6;
    int local = (i & 63) * 512 + n;
    size_t base = (size_t)(row * 4) * 32768;
    f32x4 v0 = *reinterpret_cast<const f32x4*>(hpart + base + local);
    f32x4 v1 = *reinterpret_cast<const f32x4*>(hpart + base + 32768 + local);
    f32x4 v2 = *reinterpret_cast<const f32x4*>(hpart + base + 2 * 32768 + local);
    f32x4 v3 = *reinterpret_cast<const f32x4*>(hpart + base + 3 * 32768 + local);
    f32x4 sum = (v0 + v1) + (v2 + v3);
    float dinv = rsqrtf(dd[i]);
    ushort4 o;
    o.x = f2bf(sum[0] * dinv);
    o.y = f2bf(sum[1] * dinv);
    o.z = f2bf(sum[2] * dinv);
    o.w = f2bf(sum[3] * dinv);
    *reinterpret_cast<ushort4*>(h + flat) = o;
}

// ---- K4: out = sigmoid(h @ W + b), fp32 out ----------------------------------
__global__ __launch_bounds__(512) void k_out(const unsigned short* __restrict__ h,
                                             const unsigned short* __restrict__ Wt,
                                             const float* __restrict__ b,
                                             float* __restrict__ out) {
    int bx = blockIdx.x;
    int i0 = (bx & 255) * 32, n0 = (bx >> 8) * 256;
    int tid = threadIdx.x;
    int w = tid >> 6, l = tid & 63, g = l >> 4, c = l & 15;
    int wm = w >> 2, wn = w & 3;

    float bb[4];
    #pragma unroll
    for (int nn = 0; nn < 4; ++nn) bb[nn] = b[n0 + wn * 64 + nn * 16 + c];

    f32x4 acc[4] = {};
    for (int k0 = 0; k0 < 512; k0 += 64) {
        short8 af[2];
        #pragma unroll
        for (int kk = 0; kk < 2; ++kk)
            af[kk] = ld8(h + (size_t)(i0 + wm * 16 + c) * 512 + k0 + kk * 32 + g * 8);
        #pragma unroll
        for (int kk = 0; kk < 2; ++kk)
            #pragma unroll
            for (int nn = 0; nn < 4; ++nn) {
                short8 bf = ld8(Wt + (size_t)(n0 + wn * 64 + nn * 16 + c) * 512 + k0 + kk * 32 + g * 8);
                acc[nn] = MFMA16(af[kk], bf, acc[nn]);
            }
    }
    #pragma unroll
    for (int r = 0; r < 4; ++r) {
        int row = i0 + wm * 16 + g * 4 + r;
        #pragma unroll
        for (int nn = 0; nn < 4; ++nn) {
            float z = acc[nn][r] + bb[nn];
            out[(size_t)row * 512 + n0 + wn * 64 + nn * 16 + c] = 1.f / (1.f + exp2f(-1.44269504f * z));
        }
    }
}

extern "C" void kernel_launch(void* const* d_in, const int* in_sizes, int n_in,
                              void* d_out, int out_size, void* d_ws, size_t ws_size,
                              hipStream_t stream) {
    const float* bbn = (const float*)d_in[0];   // [8192, 64]
    const float* cbn = (const float*)d_in[1];   // [8192, 512]
    const float* W   = (const float*)d_in[2];   // [512, 512]
    const float* b   = (const float*)d_in[3];   // [512]
    float* out = (float*)d_out;                 // [8192, 512] fp32

    char* ws = (char*)d_ws;
    unsigned short* bbn_h   = (unsigned short*)(ws);                    // 1 MB
    unsigned short* bbn_swz = (unsigned short*)(ws + (1u << 20));       // 1 MB
    float*          s       = (float*)(ws + (2u << 20));                // 32 KB
    float*          dd      = (float*)(ws + (2u << 20) + (1u << 15));   // 32 KB
    unsigned short* Wt      = (unsigned short*)(ws + (2u << 20) + (2u << 15));  // 512 KB
    unsigned short* cbn_sT  = (unsigned short*)(ws + (3u << 20));       // 8 MB (swizzled, dinv_j-scaled)
    unsigned short* hbuf    = (unsigned short*)(ws + (11u << 20));      // 8 MB
    unsigned short* A_swz   = (unsigned short*)(ws + (19u << 20));      // 128 MB (swizzled adjacency)
    float*          hpart   = (float*)(ws + (147u << 20));              // 64 MB (block-contiguous partials)

    k_prep_bbn<<<2048, 256, 0, stream>>>(bbn, bbn_h, bbn_swz, s);
    k_zero_d<<<8, 1024, 0, stream>>>(dd);
    k_transpose_scale<<<64, 256, 0, stream>>>(W, Wt, nullptr, 512, 512, 0);
    k_gen_adj<<<512, 512, 0, stream>>>(bbn_h, bbn_swz, s, A_swz, dd);
    k_transpose_scale<<<1024, 256, 0, stream>>>(cbn, cbn_sT, dd, 8192, 512, 1);
    k_spectral<<<512, 512, 0, stream>>>(A_swz, cbn_sT, hpart);
    k_reduce<<<4096, 256, 0, stream>>>(hpart, dd, hbuf);
    k_out<<<512, 512, 0, stream>>>(hbuf, Wt, b, out);
}

// Round 21
// 190.612 us; speedup vs baseline: 1.0740x; 1.0740x over previous
//
#include <hip/hip_runtime.h>
#include <hip/hip_bf16.h>

typedef __attribute__((ext_vector_type(8))) short short8;
typedef __attribute__((ext_vector_type(4))) float f32x4;

#define MFMA16(a, b, c) __builtin_amdgcn_mfma_f32_16x16x32_bf16((a), (b), (c), 0, 0, 0)

__device__ __forceinline__ unsigned short f2bf(float x) {
    union { float f; unsigned int u; } v; v.f = x;
    unsigned int u = v.u;
    return (unsigned short)((u + 0x7FFFu + ((u >> 16) & 1u)) >> 16);
}

__device__ __forceinline__ float bf2f(unsigned short u) {
    union { unsigned int i; float f; } v; v.i = ((unsigned)u) << 16; return v.f;
}

__device__ __forceinline__ float pow14(float x) {
    return exp2f(1.4f * log2f(x));
}

__device__ __forceinline__ short8 ld8(const unsigned short* p) {
    return *reinterpret_cast<const short8*>(p);
}

__device__ __forceinline__ void gld16(const void* src, const unsigned char* dst) {
    __builtin_amdgcn_global_load_lds(
        (const __attribute__((address_space(1))) void*)src,
        (__attribute__((address_space(3))) void*)dst, 16, 0, 0);
}

// ---- K0: bbn fp32 -> bf16 (plain + row-swizzled copy), row sums s[i] ---------
__global__ void k_prep_bbn(const float* __restrict__ bbn, unsigned short* __restrict__ bbn_h,
                           unsigned short* __restrict__ bbn_swz, float* __restrict__ s) {
    int row = blockIdx.x * 4 + (threadIdx.x >> 6);
    int lane = threadIdx.x & 63;
    float x = bbn[row * 64 + lane];
    unsigned short h = f2bf(x);
    bbn_h[row * 64 + lane] = h;
    bbn_swz[row * 64 + (lane ^ ((row & 7) << 3))] = h;
    float v = x;
    #pragma unroll
    for (int m = 1; m < 64; m <<= 1) v += __shfl_xor(v, m);
    if (lane == 0) s[row] = v;
}

__global__ void k_zero_d(float* __restrict__ dd) {
    dd[blockIdx.x * 1024 + threadIdx.x] = 0.f;
}

// ---- K0b/K2: transpose (+optional rsqrt(d) row scale, optional swizzle) ------
__global__ void k_transpose_scale(const float* __restrict__ in, unsigned short* __restrict__ out,
                                  const float* __restrict__ dvec, int K, int N, int swz) {
    __shared__ float tile[64][65];
    int tiles_k = K >> 6;
    int tk = blockIdx.x % tiles_k, tn = blockIdx.x / tiles_k;
    int k0 = tk * 64, n0 = tn * 64;
    int c = threadIdx.x & 63, rq = threadIdx.x >> 6;
    #pragma unroll
    for (int i = 0; i < 16; ++i) {
        int r = rq + 4 * i;
        float sc = dvec ? rsqrtf(dvec[k0 + r]) : 1.0f;
        tile[r][c] = in[(size_t)(k0 + r) * N + n0 + c] * sc;
    }
    __syncthreads();
    #pragma unroll
    for (int i = 0; i < 16; ++i) {
        int r = rq + 4 * i;
        int cc = swz ? (c ^ ((r & 7) << 3)) : c;
        out[(size_t)(n0 + r) * K + k0 + cc] = f2bf(tile[c][r]);
    }
}

// ---- K1: materialize A (swizzled bf16) + degree d[i] --------------------------
// 512 blocks = 128 i-tiles x 4 j-quarters; 512 threads, 8 waves, 2 blocks/CU.
// Triple-buffered Aj staged for t+2; s-quarter in LDS; counted barrier vmcnt(2).
__global__ __launch_bounds__(512, 4) void k_gen_adj(const unsigned short* __restrict__ bbn_h,
                                                    const unsigned short* __restrict__ bbn_swz,
                                                    const float* __restrict__ s,
                                                    unsigned short* __restrict__ A_swz,
                                                    float* __restrict__ dd) {
    int bx = blockIdx.x;
    int it = bx >> 2, jq = bx & 3;
    int i0 = it * 64, jbase = jq * 2048;

    int tid = threadIdx.x;
    int w = tid >> 6, l = tid & 63, g = l >> 4, c = l & 15;
    int gi = w & 3, gj2 = w >> 2;

    const unsigned short* ap = bbn_h + (i0 + gi * 16 + c) * 64;
    short8 ga0 = ld8(ap), ga1 = ld8(ap + 32);
    float si = s[i0 + gi * 16 + c];

    __shared__ unsigned char AjldsF[3 * 8192];
    __shared__ unsigned char OutldsF[2 * 8192];
    __shared__ float sLDS[2048];

    const unsigned short* ajbase = bbn_swz + (jbase + w * 8 + (l >> 3)) * 64 + (l & 7) * 8;
    const int ajdst = w * 1024;

    const int sw = (c & 7) << 4;
    const int gj0 = gj2 * 2, gj1 = gj2 * 2 + 1;
    const int bo00 = (gj0 * 16 + c) * 128 + ((g * 16) ^ sw);
    const int bo01 = (gj0 * 16 + c) * 128 + ((64 + g * 16) ^ sw);
    const int bo10 = (gj1 * 16 + c) * 128 + ((g * 16) ^ sw);
    const int bo11 = (gj1 * 16 + c) * 128 + ((64 + g * 16) ^ sw);
    const int wr0 = ((gi * 16 + c) * 128 + (gj0 * 16 + g * 4) * 2) ^ sw;
    const int wr1 = ((gi * 16 + c) * 128 + (gj1 * 16 + g * 4) * 2) ^ sw;

    float racc = 0.f;

#define GEN_TILE(T) do {                                                           \
    const unsigned char* aj = &AjldsF[((T) % 3) * 8192];                           \
    unsigned char* outp = &OutldsF[((T) & 1) * 8192];                              \
    _Pragma("unroll")                                                              \
    for (int p = 0; p < 2; ++p) {                                                  \
        short8 gb0 = *reinterpret_cast<const short8*>(&aj[p ? bo10 : bo00]);       \
        short8 gb1 = *reinterpret_cast<const short8*>(&aj[p ? bo11 : bo01]);       \
        f32x4 sj4 = *reinterpret_cast<const f32x4*>(                               \
            &sLDS[(T) * 64 + (p ? gj1 : gj0) * 16 + g * 4]);                       \
        f32x4 gf = {0.f, 0.f, 0.f, 0.f};                                           \
        gf = MFMA16(gb0, ga0, gf);                                                 \
        gf = MFMA16(gb1, ga1, gf);                                                 \
        float t0 = fmaf(2.f, gf[0], -(si + sj4[0]));                               \
        float t1 = fmaf(2.f, gf[1], -(si + sj4[1]));                               \
        float t2 = fmaf(2.f, gf[2], -(si + sj4[2]));                               \
        float t3 = fmaf(2.f, gf[3], -(si + sj4[3]));                               \
        float u0 = pow14(fmaxf(fmaf(fabsf(t0), -0.015625f, 1.f), 0.f));            \
        float u1 = pow14(fmaxf(fmaf(fabsf(t1), -0.015625f, 1.f), 0.f));            \
        float u2 = pow14(fmaxf(fmaf(fabsf(t2), -0.015625f, 1.f), 0.f));            \
        float u3 = pow14(fmaxf(fmaf(fabsf(t3), -0.015625f, 1.f), 0.f));            \
        racc += (u0 + u1) + (u2 + u3);                                             \
        unsigned short p0 = f2bf(u0), p1 = f2bf(u1), p2 = f2bf(u2), p3 = f2bf(u3); \
        *reinterpret_cast<uint2*>(&outp[p ? wr1 : wr0]) =                          \
            make_uint2((unsigned)p0 | ((unsigned)p1 << 16),                        \
                       (unsigned)p2 | ((unsigned)p3 << 16));                       \
    }                                                                              \
} while (0)

    gld16(s + jbase + w * 256 + l * 4, (unsigned char*)sLDS + w * 1024);
    gld16(ajbase, &AjldsF[ajdst]);
    gld16(ajbase + 4096, &AjldsF[8192 + ajdst]);
    asm volatile("s_waitcnt vmcnt(1) lgkmcnt(0)\ns_barrier" ::: "memory");

    for (int t = 0; t < 32; ++t) {
        if (t > 0) {
            int row = tid >> 3, seg = tid & 7;
            uint4 v = *reinterpret_cast<const uint4*>(&OutldsF[((t - 1) & 1) * 8192 + tid * 16]);
            *reinterpret_cast<uint4*>(A_swz + (size_t)(i0 + row) * 8192 + jbase + (t - 1) * 64 + seg * 8) = v;
        }
        int jt = (t + 2 < 32) ? t + 2 : 31;
        gld16(ajbase + jt * 4096, &AjldsF[((t + 2) % 3) * 8192 + ajdst]);
        GEN_TILE(t);
        if (t == 0) { asm volatile("s_waitcnt vmcnt(1) lgkmcnt(0)\ns_barrier" ::: "memory"); }
        else        { asm volatile("s_waitcnt vmcnt(2) lgkmcnt(0)\ns_barrier" ::: "memory"); }
    }
    {
        int row = tid >> 3, seg = tid & 7;
        uint4 v = *reinterpret_cast<const uint4*>(&OutldsF[(31 & 1) * 8192 + tid * 16]);
        *reinterpret_cast<uint4*>(A_swz + (size_t)(i0 + row) * 8192 + jbase + 31 * 64 + seg * 8) = v;
    }
#undef GEN_TILE

    racc += __shfl_xor(racc, 16);
    racc += __shfl_xor(racc, 32);
    if (g == 0) atomicAdd(&dd[i0 + gi * 16 + c], racc);
}

// ---- K3: split-K GEMM, BM=64 x BN=512 (full width), Ksplit=4 ------------------
// 512 blocks = 128 row x 4 ks = 2 blocks/CU; 512 thr, 8 waves, 64x64/wave.
// Partials now stored bf16 (fp32 accumulation, bf16 store) -> WRITE halves.
__global__ __launch_bounds__(512, 4) void k_spectral(const unsigned short* __restrict__ A_swz,
                                                     const unsigned short* __restrict__ cbn_sT,
                                                     unsigned short* __restrict__ hpart) {
    int bx = blockIdx.x;
    int row = bx >> 2, ks = bx & 3;
    int i0 = row * 64, k0 = ks * 2048;

    int tid = threadIdx.x;
    int w = tid >> 6, l = tid & 63, g = l >> 4, c = l & 15;
    int lrow = l >> 3, lseg = l & 7;

    __shared__ unsigned char Alds[8192];
    __shared__ unsigned char Blds[65536];

    f32x4 acc[4][4] = {};

    const unsigned short* srcA = A_swz + (size_t)(i0 + w * 8 + lrow) * 8192 + k0 + lseg * 8;
    const unsigned short* srcB = cbn_sT + (size_t)(w * 8 + lrow) * 8192 + k0 + lseg * 8;
    const int sw = (c & 7) << 4;

    for (int t = 0; t < 32; ++t) {
        int jt = t * 64;
        gld16(srcA + jt, &Alds[w * 1024]);
        #pragma unroll
        for (int q = 0; q < 8; ++q)
            gld16(srcB + (size_t)(q * 64) * 8192 + jt, &Blds[(q * 64 + w * 8) * 128]);
        asm volatile("s_waitcnt vmcnt(0) lgkmcnt(0)\ns_barrier" ::: "memory");

        #pragma unroll
        for (int kk = 0; kk < 2; ++kk) {
            short8 af[4], bf[4];
            #pragma unroll
            for (int mi = 0; mi < 4; ++mi)
                af[mi] = *reinterpret_cast<const short8*>(
                    &Alds[(mi * 16 + c) * 128 + ((kk * 64 + g * 16) ^ sw)]);
            #pragma unroll
            for (int nn = 0; nn < 4; ++nn)
                bf[nn] = *reinterpret_cast<const short8*>(
                    &Blds[(w * 64 + nn * 16 + c) * 128 + ((kk * 64 + g * 16) ^ sw)]);
            __builtin_amdgcn_s_setprio(1);
            #pragma unroll
            for (int mi = 0; mi < 4; ++mi)
                #pragma unroll
                for (int nn = 0; nn < 4; ++nn)
                    acc[mi][nn] = MFMA16(af[mi], bf[nn], acc[mi][nn]);
            __builtin_amdgcn_s_setprio(0);
        }
        asm volatile("s_waitcnt lgkmcnt(0)\ns_barrier" ::: "memory");
    }

    // epilogue: block-contiguous 64KB bf16 partial tile (64 rows x 512 cols)
    unsigned short* hp = hpart + (size_t)bx * 32768;
    #pragma unroll
    for (int mi = 0; mi < 4; ++mi)
        #pragma unroll
        for (int r = 0; r < 4; ++r) {
            int lr = mi * 16 + g * 4 + r;
            #pragma unroll
            for (int nn = 0; nn < 4; ++nn)
                hp[lr * 512 + w * 64 + nn * 16 + c] = f2bf(acc[mi][nn][r]);
        }
}

// ---- K3b: h = bf16( (Σ_ks hpart) * dinv_i ); 2048 blocks x 256 thr x 8 elems --
__global__ __launch_bounds__(256) void k_reduce(const unsigned short* __restrict__ hpart,
                                                const float* __restrict__ dd,
                                                unsigned short* __restrict__ h) {
    size_t flat = ((size_t)blockIdx.x * 256 + threadIdx.x) * 8;
    int i = (int)(flat >> 9), n = (int)(flat & 511);
    int row = i >> 6;
    size_t local = (size_t)(i & 63) * 512 + n;
    size_t base = (size_t)(row * 4) * 32768;
    uint4 p0 = *reinterpret_cast<const uint4*>(hpart + base + local);
    uint4 p1 = *reinterpret_cast<const uint4*>(hpart + base + 32768 + local);
    uint4 p2 = *reinterpret_cast<const uint4*>(hpart + base + 2 * 32768 + local);
    uint4 p3 = *reinterpret_cast<const uint4*>(hpart + base + 3 * 32768 + local);
    float dinv = rsqrtf(dd[i]);
    const unsigned* w0 = &p0.x; const unsigned* w1 = &p1.x;
    const unsigned* w2 = &p2.x; const unsigned* w3 = &p3.x;
    unsigned outw[4];
    #pragma unroll
    for (int q = 0; q < 4; ++q) {
        float lo = (bf2f((unsigned short)(w0[q] & 0xFFFF)) + bf2f((unsigned short)(w1[q] & 0xFFFF)))
                 + (bf2f((unsigned short)(w2[q] & 0xFFFF)) + bf2f((unsigned short)(w3[q] & 0xFFFF)));
        float hi = (bf2f((unsigned short)(w0[q] >> 16)) + bf2f((unsigned short)(w1[q] >> 16)))
                 + (bf2f((unsigned short)(w2[q] >> 16)) + bf2f((unsigned short)(w3[q] >> 16)));
        outw[q] = (unsigned)f2bf(lo * dinv) | ((unsigned)f2bf(hi * dinv) << 16);
    }
    *reinterpret_cast<uint4*>(h + flat) = make_uint4(outw[0], outw[1], outw[2], outw[3]);
}

// ---- K4: out = sigmoid(h @ W + b), fp32 out ----------------------------------
__global__ __launch_bounds__(512) void k_out(const unsigned short* __restrict__ h,
                                             const unsigned short* __restrict__ Wt,
                                             const float* __restrict__ b,
                                             float* __restrict__ out) {
    int bx = blockIdx.x;
    int i0 = (bx & 255) * 32, n0 = (bx >> 8) * 256;
    int tid = threadIdx.x;
    int w = tid >> 6, l = tid & 63, g = l >> 4, c = l & 15;
    int wm = w >> 2, wn = w & 3;

    float bb[4];
    #pragma unroll
    for (int nn = 0; nn < 4; ++nn) bb[nn] = b[n0 + wn * 64 + nn * 16 + c];

    f32x4 acc[4] = {};
    for (int k0 = 0; k0 < 512; k0 += 64) {
        short8 af[2];
        #pragma unroll
        for (int kk = 0; kk < 2; ++kk)
            af[kk] = ld8(h + (size_t)(i0 + wm * 16 + c) * 512 + k0 + kk * 32 + g * 8);
        #pragma unroll
        for (int kk = 0; kk < 2; ++kk)
            #pragma unroll
            for (int nn = 0; nn < 4; ++nn) {
                short8 bf = ld8(Wt + (size_t)(n0 + wn * 64 + nn * 16 + c) * 512 + k0 + kk * 32 + g * 8);
                acc[nn] = MFMA16(af[kk], bf, acc[nn]);
            }
    }
    #pragma unroll
    for (int r = 0; r < 4; ++r) {
        int row = i0 + wm * 16 + g * 4 + r;
        #pragma unroll
        for (int nn = 0; nn < 4; ++nn) {
            float z = acc[nn][r] + bb[nn];
            out[(size_t)row * 512 + n0 + wn * 64 + nn * 16 + c] = 1.f / (1.f + exp2f(-1.44269504f * z));
        }
    }
}

extern "C" void kernel_launch(void* const* d_in, const int* in_sizes, int n_in,
                              void* d_out, int out_size, void* d_ws, size_t ws_size,
                              hipStream_t stream) {
    const float* bbn = (const float*)d_in[0];   // [8192, 64]
    const float* cbn = (const float*)d_in[1];   // [8192, 512]
    const float* W   = (const float*)d_in[2];   // [512, 512]
    const float* b   = (const float*)d_in[3];   // [512]
    float* out = (float*)d_out;                 // [8192, 512] fp32

    char* ws = (char*)d_ws;
    unsigned short* bbn_h   = (unsigned short*)(ws);                    // 1 MB
    unsigned short* bbn_swz = (unsigned short*)(ws + (1u << 20));       // 1 MB
    float*          s       = (float*)(ws + (2u << 20));                // 32 KB
    float*          dd      = (float*)(ws + (2u << 20) + (1u << 15));   // 32 KB
    unsigned short* Wt      = (unsigned short*)(ws + (2u << 20) + (2u << 15));  // 512 KB
    unsigned short* cbn_sT  = (unsigned short*)(ws + (3u << 20));       // 8 MB (swizzled, dinv_j-scaled)
    unsigned short* hbuf    = (unsigned short*)(ws + (11u << 20));      // 8 MB
    unsigned short* A_swz   = (unsigned short*)(ws + (19u << 20));      // 128 MB (swizzled adjacency)
    unsigned short* hpart   = (unsigned short*)(ws + (147u << 20));     // 32 MB (bf16 block-contiguous partials)

    k_prep_bbn<<<2048, 256, 0, stream>>>(bbn, bbn_h, bbn_swz, s);
    k_zero_d<<<8, 1024, 0, stream>>>(dd);
    k_transpose_scale<<<64, 256, 0, stream>>>(W, Wt, nullptr, 512, 512, 0);
    k_gen_adj<<<512, 512, 0, stream>>>(bbn_h, bbn_swz, s, A_swz, dd);
    k_transpose_scale<<<1024, 256, 0, stream>>>(cbn, cbn_sT, dd, 8192, 512, 1);
    k_spectral<<<512, 512, 0, stream>>>(A_swz, cbn_sT, hpart);
    k_reduce<<<2048, 256, 0, stream>>>(hpart, dd, hbuf);
    k_out<<<512, 512, 0, stream>>>(hbuf, Wt, b, out);
}